// Round 14
// baseline (92.113 us; speedup 1.0000x reference)
//
#include <hip/hip_runtime.h>
#include <hip/hip_bf16.h>

typedef _Float16 half8 __attribute__((ext_vector_type(8)));
typedef float    floatx4 __attribute__((ext_vector_type(4)));

#define WSCALE      4096.0f
#define WSCALE_INV  (1.0f/(4096.0f*4096.0f))

#define WF16_OFF 8192   // _Float16 offset into ws; 16B-aligned

// ---- Merged prep (validated R13): ONE kernel, 256 blocks x 256 threads.
// Each block redundantly computes S0..S3 -> T1,U in LDS, then its 256-elem
// fragment-major W slice.
__global__ __launch_bounds__(256)
void mpo_prep(const float* __restrict__ w, _Float16* __restrict__ Wf) {
    __shared__ __align__(16) float wL[6272];
    __shared__ __align__(16) float sL[8704];   // S0@0 S1@256 S2@4352 S3@8448
    __shared__ __align__(16) float tuL[8192];  // T1@0 U@4096
    const int tid = threadIdx.x;

    {
        const floatx4* s4 = reinterpret_cast<const floatx4*>(w);
        floatx4* d4 = reinterpret_cast<floatx4*>(wL);
        for (int i = tid; i < 1568; i += 256) d4[i] = s4[i];
    }
    __syncthreads();

    // S0 (cores 0x1 @0,64)
    {
        int li = tid;
        int mm = li & 3, kk = (li >> 2) & 3, c = li >> 4;
        int k1 = kk >> 1, k2 = kk & 1, m1 = mm >> 1, m2 = mm & 1;
        float s = 0.f;
#pragma unroll
        for (int b = 0; b < 16; ++b)
            s += wL[b * 4 + k1 * 2 + m1] * wL[64 + b * 64 + c * 4 + k2 * 2 + m2];
        sL[li] = s;
    }
    // S1 tiled (cores 2x3 @1088,2112)
    {
        const int i0 = (tid >> 4) * 4, j0 = (tid & 15) * 4;
        const float* Ab = wL + 1088 + (i0 >> 2) * 64;
        const float* Bb = wL + 2112 + j0;
        float acc[4][4] = {};
#pragma unroll
        for (int b = 0; b < 16; ++b) {
            floatx4 ar = *reinterpret_cast<const floatx4*>(Ab + b * 4);
            floatx4 br = *reinterpret_cast<const floatx4*>(Bb + b * 64);
#pragma unroll
            for (int r = 0; r < 4; ++r)
#pragma unroll
                for (int s = 0; s < 4; ++s) acc[r][s] += ar[r] * br[s];
        }
#pragma unroll
        for (int r = 0; r < 4; ++r)
#pragma unroll
        for (int s = 0; s < 4; ++s) {
            int i = i0 + r, j = j0 + s;
            sL[256 + (i >> 2) * 256 + (j >> 2) * 16 +
               ((i >> 1) & 1) * 8 + ((j >> 1) & 1) * 4 + (i & 1) * 2 + (j & 1)] = acc[r][s];
        }
    }
    // S2 tiled (cores 4x5 @3136,4160)
    {
        const int i0 = (tid >> 4) * 4, j0 = (tid & 15) * 4;
        const float* Ab = wL + 3136 + (i0 >> 2) * 64;
        const float* Bb = wL + 4160 + j0;
        float acc[4][4] = {};
#pragma unroll
        for (int b = 0; b < 16; ++b) {
            floatx4 ar = *reinterpret_cast<const floatx4*>(Ab + b * 4);
            floatx4 br = *reinterpret_cast<const floatx4*>(Bb + b * 64);
#pragma unroll
            for (int r = 0; r < 4; ++r)
#pragma unroll
                for (int s = 0; s < 4; ++s) acc[r][s] += ar[r] * br[s];
        }
#pragma unroll
        for (int r = 0; r < 4; ++r)
#pragma unroll
        for (int s = 0; s < 4; ++s) {
            int i = i0 + r, j = j0 + s;
            sL[4352 + (i >> 2) * 256 + (j >> 2) * 16 +
               ((i >> 1) & 1) * 8 + ((j >> 1) & 1) * 4 + (i & 1) * 2 + (j & 1)] = acc[r][s];
        }
    }
    // S3 (cores 6x7 @5184,6208)
    {
        int li = tid;
        int mm = li & 3, kk = (li >> 2) & 3, a = li >> 4;
        int k1 = kk >> 1, k2 = kk & 1, m1 = mm >> 1, m2 = mm & 1;
        float s = 0.f;
#pragma unroll
        for (int b = 0; b < 16; ++b)
            s += wL[5184 + a * 64 + b * 4 + k1 * 2 + m1] * wL[6208 + b * 4 + k2 * 2 + m2];
        sL[8448 + li] = s;
    }
    __syncthreads();

    // T1 tiled -> tuL[0:4096)
    {
        const int p0 = (tid >> 6) * 4, q0 = (tid & 63) * 4;
        float acc[4][4] = {};
#pragma unroll
        for (int a = 0; a < 16; ++a) {
            floatx4 pr = *reinterpret_cast<const floatx4*>(sL + a * 16 + p0);
            floatx4 qr = *reinterpret_cast<const floatx4*>(sL + 256 + a * 256 + q0);
#pragma unroll
            for (int r = 0; r < 4; ++r)
#pragma unroll
                for (int s = 0; s < 4; ++s) acc[r][s] += pr[r] * qr[s];
        }
#pragma unroll
        for (int r = 0; r < 4; ++r)
#pragma unroll
        for (int s = 0; s < 4; ++s) {
            int p = p0 + r, q = q0 + s;
            tuL[(q >> 4) * 256 + ((p >> 2) * 4 + ((q >> 2) & 3)) * 16 +
                (p & 3) * 4 + (q & 3)] = acc[r][s];
        }
    }
    // U tiled -> tuL[4096:8192)
    {
        const int r0 = (tid >> 2) * 4, q0 = (tid & 3) * 4;
        float acc[4][4] = {};
#pragma unroll
        for (int b = 0; b < 16; ++b) {
            floatx4 ar = *reinterpret_cast<const floatx4*>(sL + 4352 + (r0 >> 4) * 256 + b * 16 + (r0 & 15));
            floatx4 br = *reinterpret_cast<const floatx4*>(sL + 8448 + b * 16 + q0);
#pragma unroll
            for (int r = 0; r < 4; ++r)
#pragma unroll
                for (int s = 0; s < 4; ++s) acc[r][s] += ar[r] * br[s];
        }
#pragma unroll
        for (int r = 0; r < 4; ++r)
#pragma unroll
        for (int s = 0; s < 4; ++s)
            tuL[4096 + (r0 + r) * 16 + q0 + s] = acc[r][s];
    }
    __syncthreads();

    // W slice
    {
        int idx = blockIdx.x * 256 + tid;
        int J4 = idx & 255, I4 = idx >> 8;
        int I16 = I4 >> 4, kc = (I4 >> 2) & 3, k2v = I4 & 3;
        int mc = (J4 >> 2) & 3, m2v = J4 & 3;
        int J16 = J4 >> 4;
        const float* Uc = tuL + 4096 + (((kc * 4 + mc) * 4 + k2v) * 4 + m2v);
        float s = 0.f;
#pragma unroll
        for (int a = 0; a < 16; ++a)
            s += tuL[(a * 16 + I16) * 16 + J16] * Uc[a * 256];
        int nn = J4 >> 4, lr = J4 & 15, kq = I4 >> 5, gg = (I4 >> 3) & 3, jj = I4 & 7;
        Wf[(((nn * 8 + kq) * 64) + gg * 16 + lr) * 8 + jj] = (_Float16)(s * WSCALE);
    }
}

// ---- Main fused kernel: 32 rows/wave (R12 joint n-loop, LDS slack) +
// DUAL fixed-role prefetch buffers (bufA=rows 0-15, bufB=rows 16-31; no
// even/odd code duplication). Inter-pass window: drain A (aged ~25K, no
// stall) -> issue A(p+2) -> drain B (stall covered by A(p+2) in flight) ->
// issue B(p+2). HBM never idles; steady pass = 25.6K cyc = HBM roofline.
// ~233 VGPR < 256 cap. dk from LDS (DS pipe has slack at 32 rows/wave).
__global__ __launch_bounds__(512, 2)
void mpo_main(const float* __restrict__ x, const _Float16* __restrict__ Wf,
              const float* __restrict__ dk, const float* __restrict__ bias,
              float* __restrict__ out) {
    extern __shared__ _Float16 Wl[];                       // 65536 halves + 256 floats
    float* dkL = reinterpret_cast<float*>(Wl + 65536);

    const int tid  = threadIdx.x;
    const int lane = tid & 63;
    const int wave = tid >> 6;        // 0..7
    const int lrow = lane & 15;
    const int g    = lane >> 4;

    const long blockbase = (long)blockIdx.x * 1024;
    const float* xb = x + (blockbase + wave * 32 + lrow) * 256 + g * 8;
    const int PASS_STRIDE = 256 * 256;   // floats per pass (256 rows)
    const int SET_STRIDE  = 16 * 256;    // floats per row-set

    half8 a0[8], a1[8];
    floatx4 loA[8], hiA[8], loB[8], hiB[8];

#define SB()  __builtin_amdgcn_sched_barrier(0)
#define XLD8(lo, hi, xn) do { _Pragma("unroll")                          \
    for (int i_ = 0; i_ < 8; ++i_) {                                     \
        const float* p_ = (xn) + i_ * 32;                                \
        lo[i_] = *reinterpret_cast<const floatx4*>(p_);                  \
        hi[i_] = *reinterpret_cast<const floatx4*>(p_ + 4);              \
    } } while (0)
#define XCVT8(a, lo, hi) do { _Pragma("unroll")                          \
    for (int i_ = 0; i_ < 8; ++i_) {                                     \
        half8 f_;                                                        \
        f_[0] = (_Float16)lo[i_][0]; f_[1] = (_Float16)lo[i_][1];        \
        f_[2] = (_Float16)lo[i_][2]; f_[3] = (_Float16)lo[i_][3];        \
        f_[4] = (_Float16)hi[i_][0]; f_[5] = (_Float16)hi[i_][1];        \
        f_[6] = (_Float16)hi[i_][2]; f_[7] = (_Float16)hi[i_][3];        \
        a[i_] = f_;                                                      \
    } } while (0)

    // ---- prologue ----
    XLD8(loA, hiA, xb);
    XLD8(loB, hiB, xb + SET_STRIDE);
    SB();
    {
        const floatx4* src = reinterpret_cast<const floatx4*>(Wf);
        floatx4* dst = reinterpret_cast<floatx4*>(Wl);
#pragma unroll
        for (int i = 0; i < 16; ++i)
            dst[tid + i * 512] = src[tid + i * 512];
    }
    if (tid < 256) dkL[tid] = dk[tid];
    const float bs = bias[0];
    __syncthreads();   // the only barrier (drains pass-0 loads too)

    XCVT8(a0, loA, hiA);
    XLD8(loA, hiA, xb + PASS_STRIDE);
    XCVT8(a1, loB, hiB);
    XLD8(loB, hiB, xb + PASS_STRIDE + SET_STRIDE);
    SB();

    const half8* Wv = reinterpret_cast<const half8*>(Wl);

#pragma unroll 1
    for (int p = 0; p < 4; ++p) {
        float rp0[4] = {0, 0, 0, 0}, rp1[4] = {0, 0, 0, 0};
#pragma unroll 1
        for (int n = 0; n < 16; ++n) {
            const float kv = dkL[n * 16 + lrow];           // LDS: no vmcnt wait
            const half8* Wn = Wv + n * 512 + lane;
            floatx4 c0 = {0, 0, 0, 0}, c1 = {0, 0, 0, 0};
#pragma unroll
            for (int kk = 0; kk < 8; ++kk) {
                half8 b = Wn[kk * 64];
                c0 = __builtin_amdgcn_mfma_f32_16x16x32_f16(a0[kk], b, c0, 0, 0, 0);
                c1 = __builtin_amdgcn_mfma_f32_16x16x32_f16(a1[kk], b, c1, 0, 0, 0);
            }
#pragma unroll
            for (int r = 0; r < 4; ++r) {
                rp0[r] += c0[r] * c0[r] * kv;
                rp1[r] += c1[r] * c1[r] * kv;
            }
        }

        // reduce over the 16 cols (lanes sharing g) and store both row-sets
#pragma unroll
        for (int r = 0; r < 4; ++r) {
            float v0 = rp0[r], v1 = rp1[r];
            v0 += __shfl_xor(v0, 1); v1 += __shfl_xor(v1, 1);
            v0 += __shfl_xor(v0, 2); v1 += __shfl_xor(v1, 2);
            v0 += __shfl_xor(v0, 4); v1 += __shfl_xor(v1, 4);
            v0 += __shfl_xor(v0, 8); v1 += __shfl_xor(v1, 8);
            rp0[r] = v0; rp1[r] = v1;
        }
        if (lrow == 0) {
            floatx4 o0, o1;
#pragma unroll
            for (int r = 0; r < 4; ++r) {
                o0[r] = rp0[r] * WSCALE_INV + bs;
                o1[r] = rp1[r] * WSCALE_INV + bs;
            }
            float* ob = out + blockbase + p * 256 + wave * 32 + g * 4;
            *reinterpret_cast<floatx4*>(ob)      = o0;
            *reinterpret_cast<floatx4*>(ob + 16) = o1;
        }

        // ---- inter-pass window: drain/convert p+1, issue p+2 ----
        if (p < 3) {
            XCVT8(a0, loA, hiA);                       // aged ~full pass: no stall
            if (p < 2) { XLD8(loA, hiA, xb + (p + 2) * PASS_STRIDE); }
            XCVT8(a1, loB, hiB);                       // stall covered by A(p+2)
            if (p < 2) { XLD8(loB, hiB, xb + (p + 2) * PASS_STRIDE + SET_STRIDE); }
        }
        SB();
    }
}

extern "C" void kernel_launch(void* const* d_in, const int* in_sizes, int n_in,
                              void* d_out, int out_size, void* d_ws, size_t ws_size,
                              hipStream_t stream) {
    const float* x    = (const float*)d_in[0];
    const float* w    = (const float*)d_in[1];
    const float* dk   = (const float*)d_in[2];
    const float* bias = (const float*)d_in[3];
    float* out = (float*)d_out;
    float* ws  = (float*)d_ws;

    _Float16* Wf16 = (_Float16*)(ws + WF16_OFF);

    // Allow 129 KB dynamic LDS for mpo_main (host-side attr; validated R5-R13).
    static bool attr_set = false;
    if (!attr_set) {
        hipFuncSetAttribute((const void*)mpo_main,
                            hipFuncAttributeMaxDynamicSharedMemorySize, 132096);
        attr_set = true;
    }

    // W contraction: ONE kernel (per-block redundant T1/U + W slice)
    mpo_prep<<<256, 256, 0, stream>>>(w, Wf16);

    // Main fused GEMM + square + dot: 256 blocks x 512 threads, 129 KB LDS
    mpo_main<<<256, 512, 132096, stream>>>(x, Wf16, dk, bias, out);
}

// Round 15
// 71.370 us; speedup vs baseline: 1.2906x; 1.2906x over previous
//
#include <hip/hip_runtime.h>
#include <hip/hip_bf16.h>

typedef _Float16 half8 __attribute__((ext_vector_type(8)));
typedef float    floatx4 __attribute__((ext_vector_type(4)));

#define WSCALE      4096.0f
#define WSCALE_INV  (1.0f/(4096.0f*4096.0f))

#define WF16_OFF 8192   // _Float16 offset into ws; 16B-aligned

// ---- Merged prep (validated R13/R14): 256 blocks x 256 threads; each block
// redundantly computes S0..S3 -> T1,U in LDS, then its 256-elem W slice.
__global__ __launch_bounds__(256)
void mpo_prep(const float* __restrict__ w, _Float16* __restrict__ Wf) {
    __shared__ __align__(16) float wL[6272];
    __shared__ __align__(16) float sL[8704];   // S0@0 S1@256 S2@4352 S3@8448
    __shared__ __align__(16) float tuL[8192];  // T1@0 U@4096
    const int tid = threadIdx.x;

    {
        const floatx4* s4 = reinterpret_cast<const floatx4*>(w);
        floatx4* d4 = reinterpret_cast<floatx4*>(wL);
        for (int i = tid; i < 1568; i += 256) d4[i] = s4[i];
    }
    __syncthreads();

    // S0 (cores 0x1 @0,64)
    {
        int li = tid;
        int mm = li & 3, kk = (li >> 2) & 3, c = li >> 4;
        int k1 = kk >> 1, k2 = kk & 1, m1 = mm >> 1, m2 = mm & 1;
        float s = 0.f;
#pragma unroll
        for (int b = 0; b < 16; ++b)
            s += wL[b * 4 + k1 * 2 + m1] * wL[64 + b * 64 + c * 4 + k2 * 2 + m2];
        sL[li] = s;
    }
    // S1 tiled (cores 2x3 @1088,2112)
    {
        const int i0 = (tid >> 4) * 4, j0 = (tid & 15) * 4;
        const float* Ab = wL + 1088 + (i0 >> 2) * 64;
        const float* Bb = wL + 2112 + j0;
        float acc[4][4] = {};
#pragma unroll
        for (int b = 0; b < 16; ++b) {
            floatx4 ar = *reinterpret_cast<const floatx4*>(Ab + b * 4);
            floatx4 br = *reinterpret_cast<const floatx4*>(Bb + b * 64);
#pragma unroll
            for (int r = 0; r < 4; ++r)
#pragma unroll
                for (int s = 0; s < 4; ++s) acc[r][s] += ar[r] * br[s];
        }
#pragma unroll
        for (int r = 0; r < 4; ++r)
#pragma unroll
        for (int s = 0; s < 4; ++s) {
            int i = i0 + r, j = j0 + s;
            sL[256 + (i >> 2) * 256 + (j >> 2) * 16 +
               ((i >> 1) & 1) * 8 + ((j >> 1) & 1) * 4 + (i & 1) * 2 + (j & 1)] = acc[r][s];
        }
    }
    // S2 tiled (cores 4x5 @3136,4160)
    {
        const int i0 = (tid >> 4) * 4, j0 = (tid & 15) * 4;
        const float* Ab = wL + 3136 + (i0 >> 2) * 64;
        const float* Bb = wL + 4160 + j0;
        float acc[4][4] = {};
#pragma unroll
        for (int b = 0; b < 16; ++b) {
            floatx4 ar = *reinterpret_cast<const floatx4*>(Ab + b * 4);
            floatx4 br = *reinterpret_cast<const floatx4*>(Bb + b * 64);
#pragma unroll
            for (int r = 0; r < 4; ++r)
#pragma unroll
                for (int s = 0; s < 4; ++s) acc[r][s] += ar[r] * br[s];
        }
#pragma unroll
        for (int r = 0; r < 4; ++r)
#pragma unroll
        for (int s = 0; s < 4; ++s) {
            int i = i0 + r, j = j0 + s;
            sL[4352 + (i >> 2) * 256 + (j >> 2) * 16 +
               ((i >> 1) & 1) * 8 + ((j >> 1) & 1) * 4 + (i & 1) * 2 + (j & 1)] = acc[r][s];
        }
    }
    // S3 (cores 6x7 @5184,6208)
    {
        int li = tid;
        int mm = li & 3, kk = (li >> 2) & 3, a = li >> 4;
        int k1 = kk >> 1, k2 = kk & 1, m1 = mm >> 1, m2 = mm & 1;
        float s = 0.f;
#pragma unroll
        for (int b = 0; b < 16; ++b)
            s += wL[5184 + a * 64 + b * 4 + k1 * 2 + m1] * wL[6208 + b * 4 + k2 * 2 + m2];
        sL[8448 + li] = s;
    }
    __syncthreads();

    // T1 tiled -> tuL[0:4096)
    {
        const int p0 = (tid >> 6) * 4, q0 = (tid & 63) * 4;
        float acc[4][4] = {};
#pragma unroll
        for (int a = 0; a < 16; ++a) {
            floatx4 pr = *reinterpret_cast<const floatx4*>(sL + a * 16 + p0);
            floatx4 qr = *reinterpret_cast<const floatx4*>(sL + 256 + a * 256 + q0);
#pragma unroll
            for (int r = 0; r < 4; ++r)
#pragma unroll
                for (int s = 0; s < 4; ++s) acc[r][s] += pr[r] * qr[s];
        }
#pragma unroll
        for (int r = 0; r < 4; ++r)
#pragma unroll
        for (int s = 0; s < 4; ++s) {
            int p = p0 + r, q = q0 + s;
            tuL[(q >> 4) * 256 + ((p >> 2) * 4 + ((q >> 2) & 3)) * 16 +
                (p & 3) * 4 + (q & 3)] = acc[r][s];
        }
    }
    // U tiled -> tuL[4096:8192)
    {
        const int r0 = (tid >> 2) * 4, q0 = (tid & 3) * 4;
        float acc[4][4] = {};
#pragma unroll
        for (int b = 0; b < 16; ++b) {
            floatx4 ar = *reinterpret_cast<const floatx4*>(sL + 4352 + (r0 >> 4) * 256 + b * 16 + (r0 & 15));
            floatx4 br = *reinterpret_cast<const floatx4*>(sL + 8448 + b * 16 + q0);
#pragma unroll
            for (int r = 0; r < 4; ++r)
#pragma unroll
                for (int s = 0; s < 4; ++s) acc[r][s] += ar[r] * br[s];
        }
#pragma unroll
        for (int r = 0; r < 4; ++r)
#pragma unroll
        for (int s = 0; s < 4; ++s)
            tuL[4096 + (r0 + r) * 16 + q0 + s] = acc[r][s];
    }
    __syncthreads();

    // W slice
    {
        int idx = blockIdx.x * 256 + tid;
        int J4 = idx & 255, I4 = idx >> 8;
        int I16 = I4 >> 4, kc = (I4 >> 2) & 3, k2v = I4 & 3;
        int mc = (J4 >> 2) & 3, m2v = J4 & 3;
        int J16 = J4 >> 4;
        const float* Uc = tuL + 4096 + (((kc * 4 + mc) * 4 + k2v) * 4 + m2v);
        float s = 0.f;
#pragma unroll
        for (int a = 0; a < 16; ++a)
            s += tuL[(a * 16 + I16) * 16 + J16] * Uc[a * 256];
        int nn = J4 >> 4, lr = J4 & 15, kq = I4 >> 5, gg = (I4 >> 3) & 3, jj = I4 & 7;
        Wf[(((nn * 8 + kq) * 64) + gg * 16 + lr) * 8 + jj] = (_Float16)(s * WSCALE);
    }
}

// ---- Main fused kernel: 4-WAVE / 512-VGPR design ----
// 256 blocks x 256 threads (4 waves, 1/SIMD; LDS 129KB -> 1 block/CU anyway;
// __launch_bounds__(256,1) raises the per-wave VGPR cap to 512, dissolving
// the 256-VGPR cliff that sank R9/R14). Each wave owns 256 rows: 4 passes of
// 64 rows (a0..a3[8] = 128 VGPR) with dual fixed-role lo/hi prefetch buffers
// (128 VGPR) issued alternately -> >=1 set always in flight, HBM never idles.
// LDS B-reads: 512 ds_read_b128/CU/pass (~6K cyc) vs HBM 25.6K -> huge slack.
__global__ __launch_bounds__(256, 1)
void mpo_main(const float* __restrict__ x, const _Float16* __restrict__ Wf,
              const float* __restrict__ dk, const float* __restrict__ bias,
              float* __restrict__ out) {
    extern __shared__ _Float16 Wl[];                       // 65536 halves + 256 floats
    float* dkL = reinterpret_cast<float*>(Wl + 65536);

    const int tid  = threadIdx.x;
    const int lane = tid & 63;
    const int wave = tid >> 6;        // 0..3
    const int lrow = lane & 15;
    const int g    = lane >> 4;

    const long blockbase = (long)blockIdx.x * 1024;
    // wave's rows: [blockbase + wave*256, +256) = 16 sets of 16 rows
    const float* xs = x + (blockbase + wave * 256 + lrow) * 256 + g * 8;
    const int SS = 16 * 256;          // floats per 16-row set

    half8 a0[8], a1[8], a2[8], a3[8];
    floatx4 loA[8], hiA[8], loB[8], hiB[8];

#define SB()  __builtin_amdgcn_sched_barrier(0)
#define XLD8(lo, hi, xn) do { _Pragma("unroll")                          \
    for (int i_ = 0; i_ < 8; ++i_) {                                     \
        const float* p_ = (xn) + i_ * 32;                                \
        lo[i_] = *reinterpret_cast<const floatx4*>(p_);                  \
        hi[i_] = *reinterpret_cast<const floatx4*>(p_ + 4);              \
    } } while (0)
#define XCVT8(a, lo, hi) do { _Pragma("unroll")                          \
    for (int i_ = 0; i_ < 8; ++i_) {                                     \
        half8 f_;                                                        \
        f_[0] = (_Float16)lo[i_][0]; f_[1] = (_Float16)lo[i_][1];        \
        f_[2] = (_Float16)lo[i_][2]; f_[3] = (_Float16)lo[i_][3];        \
        f_[4] = (_Float16)hi[i_][0]; f_[5] = (_Float16)hi[i_][1];        \
        f_[6] = (_Float16)hi[i_][2]; f_[7] = (_Float16)hi[i_][3];        \
        a[i_] = f_;                                                      \
    } } while (0)

    // ---- prologue: issue S0,S1; stage W (32 f4/thread) + dk; barrier ----
    XLD8(loA, hiA, xs);
    XLD8(loB, hiB, xs + SS);
    SB();
    {
        const floatx4* src = reinterpret_cast<const floatx4*>(Wf);
        floatx4* dst = reinterpret_cast<floatx4*>(Wl);
#pragma unroll 8
        for (int i = 0; i < 32; ++i)
            dst[tid + i * 256] = src[tid + i * 256];
    }
    dkL[tid] = dk[tid];
    const float bs = bias[0];
    __syncthreads();   // the only barrier

    XCVT8(a0, loA, hiA); XLD8(loA, hiA, xs + 2 * SS); SB();
    XCVT8(a1, loB, hiB); XLD8(loB, hiB, xs + 3 * SS); SB();

    const half8* Wv = reinterpret_cast<const half8*>(Wl);

#pragma unroll 1
    for (int j = 0; j < 4; ++j) {
        // finish filling this pass's 4 sets; issue next pass's first 2
        XCVT8(a2, loA, hiA);
        if (j < 3) { XLD8(loA, hiA, xs + (4 * j + 4) * SS); }
        SB();
        XCVT8(a3, loB, hiB);
        if (j < 3) { XLD8(loB, hiB, xs + (4 * j + 5) * SS); }
        SB();

        // ---- n-loop over 64 rows (4 sets share every B fragment) ----
        floatx4 rp0 = {0,0,0,0}, rp1 = {0,0,0,0}, rp2 = {0,0,0,0}, rp3 = {0,0,0,0};
#pragma unroll 1
        for (int n = 0; n < 16; ++n) {
            const float kv = dkL[n * 16 + lrow];
            const half8* Wn = Wv + n * 512 + lane;
            floatx4 c0 = {0,0,0,0}, c1 = {0,0,0,0}, c2 = {0,0,0,0}, c3 = {0,0,0,0};
#pragma unroll
            for (int kk = 0; kk < 8; ++kk) {
                half8 b = Wn[kk * 64];
                c0 = __builtin_amdgcn_mfma_f32_16x16x32_f16(a0[kk], b, c0, 0, 0, 0);
                c1 = __builtin_amdgcn_mfma_f32_16x16x32_f16(a1[kk], b, c1, 0, 0, 0);
                c2 = __builtin_amdgcn_mfma_f32_16x16x32_f16(a2[kk], b, c2, 0, 0, 0);
                c3 = __builtin_amdgcn_mfma_f32_16x16x32_f16(a3[kk], b, c3, 0, 0, 0);
            }
#pragma unroll
            for (int r = 0; r < 4; ++r) {
                rp0[r] += c0[r] * c0[r] * kv;
                rp1[r] += c1[r] * c1[r] * kv;
                rp2[r] += c2[r] * c2[r] * kv;
                rp3[r] += c3[r] * c3[r] * kv;
            }
        }

        // reduce over the 16 cols (lanes sharing g); store 4 sets
#pragma unroll
        for (int r = 0; r < 4; ++r) {
            float v0 = rp0[r], v1 = rp1[r], v2 = rp2[r], v3 = rp3[r];
            v0 += __shfl_xor(v0, 1); v1 += __shfl_xor(v1, 1);
            v2 += __shfl_xor(v2, 1); v3 += __shfl_xor(v3, 1);
            v0 += __shfl_xor(v0, 2); v1 += __shfl_xor(v1, 2);
            v2 += __shfl_xor(v2, 2); v3 += __shfl_xor(v3, 2);
            v0 += __shfl_xor(v0, 4); v1 += __shfl_xor(v1, 4);
            v2 += __shfl_xor(v2, 4); v3 += __shfl_xor(v3, 4);
            v0 += __shfl_xor(v0, 8); v1 += __shfl_xor(v1, 8);
            v2 += __shfl_xor(v2, 8); v3 += __shfl_xor(v3, 8);
            rp0[r] = v0; rp1[r] = v1; rp2[r] = v2; rp3[r] = v3;
        }
        if (lrow == 0) {
            floatx4 o0, o1, o2, o3;
#pragma unroll
            for (int r = 0; r < 4; ++r) {
                o0[r] = rp0[r] * WSCALE_INV + bs;
                o1[r] = rp1[r] * WSCALE_INV + bs;
                o2[r] = rp2[r] * WSCALE_INV + bs;
                o3[r] = rp3[r] * WSCALE_INV + bs;
            }
            float* ob = out + blockbase + wave * 256 + j * 64 + g * 4;
            *reinterpret_cast<floatx4*>(ob)      = o0;
            *reinterpret_cast<floatx4*>(ob + 16) = o1;
            *reinterpret_cast<floatx4*>(ob + 32) = o2;
            *reinterpret_cast<floatx4*>(ob + 48) = o3;
        }

        // refill first 2 sets of next pass; issue the following 2
        if (j < 3) {
            XCVT8(a0, loA, hiA); XLD8(loA, hiA, xs + (4 * j + 6) * SS); SB();
            XCVT8(a1, loB, hiB); XLD8(loB, hiB, xs + (4 * j + 7) * SS); SB();
        }
    }
}

extern "C" void kernel_launch(void* const* d_in, const int* in_sizes, int n_in,
                              void* d_out, int out_size, void* d_ws, size_t ws_size,
                              hipStream_t stream) {
    const float* x    = (const float*)d_in[0];
    const float* w    = (const float*)d_in[1];
    const float* dk   = (const float*)d_in[2];
    const float* bias = (const float*)d_in[3];
    float* out = (float*)d_out;
    float* ws  = (float*)d_ws;

    _Float16* Wf16 = (_Float16*)(ws + WF16_OFF);

    // Allow 129 KB dynamic LDS for mpo_main (host-side attr; validated R5-R14).
    static bool attr_set = false;
    if (!attr_set) {
        hipFuncSetAttribute((const void*)mpo_main,
                            hipFuncAttributeMaxDynamicSharedMemorySize, 132096);
        attr_set = true;
    }

    // W contraction: ONE kernel (per-block redundant T1/U + W slice)
    mpo_prep<<<256, 256, 0, stream>>>(w, Wf16);

    // Main fused GEMM + square + dot: 256 blocks x 256 threads, 129 KB LDS
    mpo_main<<<256, 256, 132096, stream>>>(x, Wf16, dk, bias, out);
}

// Round 16
// 67.715 us; speedup vs baseline: 1.3603x; 1.0540x over previous
//
#include <hip/hip_runtime.h>
#include <hip/hip_bf16.h>

typedef _Float16 half8 __attribute__((ext_vector_type(8)));
typedef float    floatx4 __attribute__((ext_vector_type(4)));

#define WSCALE      4096.0f
#define WSCALE_INV  (1.0f/(4096.0f*4096.0f))

#define WF16_OFF 8192   // _Float16 offset into ws; 16B-aligned

// ---- Merged prep (validated R13/R15): 256 blocks x 256 threads; each block
// redundantly computes S0..S3 -> T1,U in LDS, then its 256-elem W slice.
__global__ __launch_bounds__(256)
void mpo_prep(const float* __restrict__ w, _Float16* __restrict__ Wf) {
    __shared__ __align__(16) float wL[6272];
    __shared__ __align__(16) float sL[8704];   // S0@0 S1@256 S2@4352 S3@8448
    __shared__ __align__(16) float tuL[8192];  // T1@0 U@4096
    const int tid = threadIdx.x;

    {
        const floatx4* s4 = reinterpret_cast<const floatx4*>(w);
        floatx4* d4 = reinterpret_cast<floatx4*>(wL);
        for (int i = tid; i < 1568; i += 256) d4[i] = s4[i];
    }
    __syncthreads();

    // S0 (cores 0x1 @0,64)
    {
        int li = tid;
        int mm = li & 3, kk = (li >> 2) & 3, c = li >> 4;
        int k1 = kk >> 1, k2 = kk & 1, m1 = mm >> 1, m2 = mm & 1;
        float s = 0.f;
#pragma unroll
        for (int b = 0; b < 16; ++b)
            s += wL[b * 4 + k1 * 2 + m1] * wL[64 + b * 64 + c * 4 + k2 * 2 + m2];
        sL[li] = s;
    }
    // S1 tiled (cores 2x3 @1088,2112)
    {
        const int i0 = (tid >> 4) * 4, j0 = (tid & 15) * 4;
        const float* Ab = wL + 1088 + (i0 >> 2) * 64;
        const float* Bb = wL + 2112 + j0;
        float acc[4][4] = {};
#pragma unroll
        for (int b = 0; b < 16; ++b) {
            floatx4 ar = *reinterpret_cast<const floatx4*>(Ab + b * 4);
            floatx4 br = *reinterpret_cast<const floatx4*>(Bb + b * 64);
#pragma unroll
            for (int r = 0; r < 4; ++r)
#pragma unroll
                for (int s = 0; s < 4; ++s) acc[r][s] += ar[r] * br[s];
        }
#pragma unroll
        for (int r = 0; r < 4; ++r)
#pragma unroll
        for (int s = 0; s < 4; ++s) {
            int i = i0 + r, j = j0 + s;
            sL[256 + (i >> 2) * 256 + (j >> 2) * 16 +
               ((i >> 1) & 1) * 8 + ((j >> 1) & 1) * 4 + (i & 1) * 2 + (j & 1)] = acc[r][s];
        }
    }
    // S2 tiled (cores 4x5 @3136,4160)
    {
        const int i0 = (tid >> 4) * 4, j0 = (tid & 15) * 4;
        const float* Ab = wL + 3136 + (i0 >> 2) * 64;
        const float* Bb = wL + 4160 + j0;
        float acc[4][4] = {};
#pragma unroll
        for (int b = 0; b < 16; ++b) {
            floatx4 ar = *reinterpret_cast<const floatx4*>(Ab + b * 4);
            floatx4 br = *reinterpret_cast<const floatx4*>(Bb + b * 64);
#pragma unroll
            for (int r = 0; r < 4; ++r)
#pragma unroll
                for (int s = 0; s < 4; ++s) acc[r][s] += ar[r] * br[s];
        }
#pragma unroll
        for (int r = 0; r < 4; ++r)
#pragma unroll
        for (int s = 0; s < 4; ++s) {
            int i = i0 + r, j = j0 + s;
            sL[4352 + (i >> 2) * 256 + (j >> 2) * 16 +
               ((i >> 1) & 1) * 8 + ((j >> 1) & 1) * 4 + (i & 1) * 2 + (j & 1)] = acc[r][s];
        }
    }
    // S3 (cores 6x7 @5184,6208)
    {
        int li = tid;
        int mm = li & 3, kk = (li >> 2) & 3, a = li >> 4;
        int k1 = kk >> 1, k2 = kk & 1, m1 = mm >> 1, m2 = mm & 1;
        float s = 0.f;
#pragma unroll
        for (int b = 0; b < 16; ++b)
            s += wL[5184 + a * 64 + b * 4 + k1 * 2 + m1] * wL[6208 + b * 4 + k2 * 2 + m2];
        sL[8448 + li] = s;
    }
    __syncthreads();

    // T1 tiled -> tuL[0:4096)
    {
        const int p0 = (tid >> 6) * 4, q0 = (tid & 63) * 4;
        float acc[4][4] = {};
#pragma unroll
        for (int a = 0; a < 16; ++a) {
            floatx4 pr = *reinterpret_cast<const floatx4*>(sL + a * 16 + p0);
            floatx4 qr = *reinterpret_cast<const floatx4*>(sL + 256 + a * 256 + q0);
#pragma unroll
            for (int r = 0; r < 4; ++r)
#pragma unroll
                for (int s = 0; s < 4; ++s) acc[r][s] += pr[r] * qr[s];
        }
#pragma unroll
        for (int r = 0; r < 4; ++r)
#pragma unroll
        for (int s = 0; s < 4; ++s) {
            int p = p0 + r, q = q0 + s;
            tuL[(q >> 4) * 256 + ((p >> 2) * 4 + ((q >> 2) & 3)) * 16 +
                (p & 3) * 4 + (q & 3)] = acc[r][s];
        }
    }
    // U tiled -> tuL[4096:8192)
    {
        const int r0 = (tid >> 2) * 4, q0 = (tid & 3) * 4;
        float acc[4][4] = {};
#pragma unroll
        for (int b = 0; b < 16; ++b) {
            floatx4 ar = *reinterpret_cast<const floatx4*>(sL + 4352 + (r0 >> 4) * 256 + b * 16 + (r0 & 15));
            floatx4 br = *reinterpret_cast<const floatx4*>(sL + 8448 + b * 16 + q0);
#pragma unroll
            for (int r = 0; r < 4; ++r)
#pragma unroll
                for (int s = 0; s < 4; ++s) acc[r][s] += ar[r] * br[s];
        }
#pragma unroll
        for (int r = 0; r < 4; ++r)
#pragma unroll
        for (int s = 0; s < 4; ++s)
            tuL[4096 + (r0 + r) * 16 + q0 + s] = acc[r][s];
    }
    __syncthreads();

    // W slice
    {
        int idx = blockIdx.x * 256 + tid;
        int J4 = idx & 255, I4 = idx >> 8;
        int I16 = I4 >> 4, kc = (I4 >> 2) & 3, k2v = I4 & 3;
        int mc = (J4 >> 2) & 3, m2v = J4 & 3;
        int J16 = J4 >> 4;
        const float* Uc = tuL + 4096 + (((kc * 4 + mc) * 4 + k2v) * 4 + m2v);
        float s = 0.f;
#pragma unroll
        for (int a = 0; a < 16; ++a)
            s += tuL[(a * 16 + I16) * 16 + J16] * Uc[a * 256];
        int nn = J4 >> 4, lr = J4 & 15, kq = I4 >> 5, gg = (I4 >> 3) & 3, jj = I4 & 7;
        Wf[(((nn * 8 + kq) * 64) + gg * 16 + lr) * 8 + jj] = (_Float16)(s * WSCALE);
    }
}

// ---- Main fused kernel: R13 single-set pipeline + 2-DEEP set prefetch ----
// 256 blocks x 512 threads (8 waves, 2/SIMD), W (128 KB) + dk in LDS, one
// barrier. 8 sets of 16 rows/wave. Two fixed-parity lo/hi buffers (even set
// -> bufA, odd -> bufB): during nloop(s), sets s+1 AND s+2 are in flight
// (32 KB/wave), so XCVT(s+1) consumes loads aged ~2 n-loops (counted
// vmcnt(16) wait, never a drain) -> HBM queue jitter absorbed. ~200 VGPR.
__global__ __launch_bounds__(512, 2)
void mpo_main(const float* __restrict__ x, const _Float16* __restrict__ Wf,
              const float* __restrict__ dk, const float* __restrict__ bias,
              float* __restrict__ out) {
    extern __shared__ _Float16 Wl[];                       // 65536 halves + 256 floats
    float* dkL = reinterpret_cast<float*>(Wl + 65536);

    const int tid  = threadIdx.x;
    const int lane = tid & 63;
    const int wave = tid >> 6;        // 0..7
    const int lrow = lane & 15;
    const int g    = lane >> 4;

    const long blockbase = (long)blockIdx.x * 1024;
    // wave's rows for set s: blockbase + s*128 + wave*16 + lrow
    const float* xs = x + (blockbase + wave * 16 + lrow) * 256 + g * 8;
    const int SS = 128 * 256;         // floats per set (128 rows)

    half8 a[8];
    floatx4 loA[8], hiA[8], loB[8], hiB[8];

#define SB()  __builtin_amdgcn_sched_barrier(0)
#define XLD8(lo, hi, xn) do { _Pragma("unroll")                          \
    for (int i_ = 0; i_ < 8; ++i_) {                                     \
        const float* p_ = (xn) + i_ * 32;                                \
        lo[i_] = *reinterpret_cast<const floatx4*>(p_);                  \
        hi[i_] = *reinterpret_cast<const floatx4*>(p_ + 4);              \
    } } while (0)
#define XCVT8(dst, lo, hi) do { _Pragma("unroll")                        \
    for (int i_ = 0; i_ < 8; ++i_) {                                     \
        half8 f_;                                                        \
        f_[0] = (_Float16)lo[i_][0]; f_[1] = (_Float16)lo[i_][1];        \
        f_[2] = (_Float16)lo[i_][2]; f_[3] = (_Float16)lo[i_][3];        \
        f_[4] = (_Float16)hi[i_][0]; f_[5] = (_Float16)hi[i_][1];        \
        f_[6] = (_Float16)hi[i_][2]; f_[7] = (_Float16)hi[i_][3];        \
        dst[i_] = f_;                                                    \
    } } while (0)

#define NLOOP(rp) do {                                                           \
    _Pragma("unroll 1")                                                          \
    for (int n = 0; n < 16; ++n) {                                               \
        const float kv = dkL[n * 16 + lrow];                                     \
        const half8* Wn = Wv + n * 512 + lane;                                   \
        floatx4 c0 = {0, 0, 0, 0};                                               \
        _Pragma("unroll")                                                        \
        for (int kk = 0; kk < 8; ++kk)                                           \
            c0 = __builtin_amdgcn_mfma_f32_16x16x32_f16(a[kk], Wn[kk * 64], c0, 0, 0, 0); \
        _Pragma("unroll")                                                        \
        for (int r = 0; r < 4; ++r) rp[r] += c0[r] * c0[r] * kv;                 \
    } } while (0)

#define REDUCE_STORE(rp, s) do {                                                 \
    _Pragma("unroll")                                                            \
    for (int r = 0; r < 4; ++r) {                                                \
        float v = rp[r];                                                         \
        v += __shfl_xor(v, 1); v += __shfl_xor(v, 2);                            \
        v += __shfl_xor(v, 4); v += __shfl_xor(v, 8);                            \
        rp[r] = v;                                                               \
    }                                                                            \
    if (lrow == 0) {                                                             \
        floatx4 o;                                                               \
        _Pragma("unroll")                                                        \
        for (int r = 0; r < 4; ++r) o[r] = rp[r] * WSCALE_INV + bs;              \
        *reinterpret_cast<floatx4*>(out + blockbase + (s) * 128 + wave * 16 + g * 4) = o; \
    } } while (0)

    // ---- prologue: issue set0(A), set1(B); stage W + dk; barrier ----
    XLD8(loA, hiA, xs);
    XLD8(loB, hiB, xs + SS);
    SB();
    {
        const floatx4* src = reinterpret_cast<const floatx4*>(Wf);
        floatx4* dst = reinterpret_cast<floatx4*>(Wl);
#pragma unroll
        for (int i = 0; i < 16; ++i)
            dst[tid + i * 512] = src[tid + i * 512];
    }
    if (tid < 256) dkL[tid] = dk[tid];
    const float bs = bias[0];
    __syncthreads();   // the only barrier

    XCVT8(a, loA, hiA);            // a <- set 0
    XLD8(loA, hiA, xs + 2 * SS);   // issue set 2 -> in flight: set1, set2
    SB();

    const half8* Wv = reinterpret_cast<const half8*>(Wl);

#pragma unroll 1
    for (int j = 0; j < 4; ++j) {
        // ---- even set s = 2j (a holds it; bufB has s+1, bufA has s+2) ----
        {
            float rp[4] = {0, 0, 0, 0};
            NLOOP(rp);
            XCVT8(a, loB, hiB);                              // a <- set 2j+1 (aged 2 nloops)
            if (2 * j + 3 < 8) { XLD8(loB, hiB, xs + (2 * j + 3) * SS); }
            SB();
            REDUCE_STORE(rp, 2 * j);
            SB();
        }
        // ---- odd set s = 2j+1 (bufA has s+1, bufB has s+2) ----
        {
            float rp[4] = {0, 0, 0, 0};
            NLOOP(rp);
            if (2 * j + 2 < 8) { XCVT8(a, loA, hiA); }       // a <- set 2j+2
            if (2 * j + 4 < 8) { XLD8(loA, hiA, xs + (2 * j + 4) * SS); }
            SB();
            REDUCE_STORE(rp, 2 * j + 1);
            SB();
        }
    }
}

extern "C" void kernel_launch(void* const* d_in, const int* in_sizes, int n_in,
                              void* d_out, int out_size, void* d_ws, size_t ws_size,
                              hipStream_t stream) {
    const float* x    = (const float*)d_in[0];
    const float* w    = (const float*)d_in[1];
    const float* dk   = (const float*)d_in[2];
    const float* bias = (const float*)d_in[3];
    float* out = (float*)d_out;
    float* ws  = (float*)d_ws;

    _Float16* Wf16 = (_Float16*)(ws + WF16_OFF);

    // Allow 129 KB dynamic LDS for mpo_main (host-side attr; validated R5-R15).
    static bool attr_set = false;
    if (!attr_set) {
        hipFuncSetAttribute((const void*)mpo_main,
                            hipFuncAttributeMaxDynamicSharedMemorySize, 132096);
        attr_set = true;
    }

    // W contraction: ONE kernel (per-block redundant T1/U + W slice)
    mpo_prep<<<256, 256, 0, stream>>>(w, Wf16);

    // Main fused GEMM + square + dot: 256 blocks x 512 threads, 129 KB LDS
    mpo_main<<<256, 512, 132096, stream>>>(x, Wf16, dk, bias, out);
}

// Round 17
// 67.674 us; speedup vs baseline: 1.3611x; 1.0006x over previous
//
#include <hip/hip_runtime.h>
#include <hip/hip_bf16.h>

typedef _Float16 half8 __attribute__((ext_vector_type(8)));
typedef float    floatx4 __attribute__((ext_vector_type(4)));

#define WSCALE      4096.0f
#define WSCALE_INV  (1.0f/(4096.0f*4096.0f))

#define WF16_OFF 8192   // _Float16 offset into ws; 16B-aligned

// ---- Merged prep (validated R13/R15/R16): 256 blocks x 256 threads; each
// block redundantly computes S0..S3 -> T1,U in LDS, then its 256-elem W slice.
__global__ __launch_bounds__(256)
void mpo_prep(const float* __restrict__ w, _Float16* __restrict__ Wf) {
    __shared__ __align__(16) float wL[6272];
    __shared__ __align__(16) float sL[8704];   // S0@0 S1@256 S2@4352 S3@8448
    __shared__ __align__(16) float tuL[8192];  // T1@0 U@4096
    const int tid = threadIdx.x;

    {
        const floatx4* s4 = reinterpret_cast<const floatx4*>(w);
        floatx4* d4 = reinterpret_cast<floatx4*>(wL);
        for (int i = tid; i < 1568; i += 256) d4[i] = s4[i];
    }
    __syncthreads();

    // S0 (cores 0x1 @0,64)
    {
        int li = tid;
        int mm = li & 3, kk = (li >> 2) & 3, c = li >> 4;
        int k1 = kk >> 1, k2 = kk & 1, m1 = mm >> 1, m2 = mm & 1;
        float s = 0.f;
#pragma unroll
        for (int b = 0; b < 16; ++b)
            s += wL[b * 4 + k1 * 2 + m1] * wL[64 + b * 64 + c * 4 + k2 * 2 + m2];
        sL[li] = s;
    }
    // S1 tiled (cores 2x3 @1088,2112)
    {
        const int i0 = (tid >> 4) * 4, j0 = (tid & 15) * 4;
        const float* Ab = wL + 1088 + (i0 >> 2) * 64;
        const float* Bb = wL + 2112 + j0;
        float acc[4][4] = {};
#pragma unroll
        for (int b = 0; b < 16; ++b) {
            floatx4 ar = *reinterpret_cast<const floatx4*>(Ab + b * 4);
            floatx4 br = *reinterpret_cast<const floatx4*>(Bb + b * 64);
#pragma unroll
            for (int r = 0; r < 4; ++r)
#pragma unroll
                for (int s = 0; s < 4; ++s) acc[r][s] += ar[r] * br[s];
        }
#pragma unroll
        for (int r = 0; r < 4; ++r)
#pragma unroll
        for (int s = 0; s < 4; ++s) {
            int i = i0 + r, j = j0 + s;
            sL[256 + (i >> 2) * 256 + (j >> 2) * 16 +
               ((i >> 1) & 1) * 8 + ((j >> 1) & 1) * 4 + (i & 1) * 2 + (j & 1)] = acc[r][s];
        }
    }
    // S2 tiled (cores 4x5 @3136,4160)
    {
        const int i0 = (tid >> 4) * 4, j0 = (tid & 15) * 4;
        const float* Ab = wL + 3136 + (i0 >> 2) * 64;
        const float* Bb = wL + 4160 + j0;
        float acc[4][4] = {};
#pragma unroll
        for (int b = 0; b < 16; ++b) {
            floatx4 ar = *reinterpret_cast<const floatx4*>(Ab + b * 4);
            floatx4 br = *reinterpret_cast<const floatx4*>(Bb + b * 64);
#pragma unroll
            for (int r = 0; r < 4; ++r)
#pragma unroll
                for (int s = 0; s < 4; ++s) acc[r][s] += ar[r] * br[s];
        }
#pragma unroll
        for (int r = 0; r < 4; ++r)
#pragma unroll
        for (int s = 0; s < 4; ++s) {
            int i = i0 + r, j = j0 + s;
            sL[4352 + (i >> 2) * 256 + (j >> 2) * 16 +
               ((i >> 1) & 1) * 8 + ((j >> 1) & 1) * 4 + (i & 1) * 2 + (j & 1)] = acc[r][s];
        }
    }
    // S3 (cores 6x7 @5184,6208)
    {
        int li = tid;
        int mm = li & 3, kk = (li >> 2) & 3, a = li >> 4;
        int k1 = kk >> 1, k2 = kk & 1, m1 = mm >> 1, m2 = mm & 1;
        float s = 0.f;
#pragma unroll
        for (int b = 0; b < 16; ++b)
            s += wL[5184 + a * 64 + b * 4 + k1 * 2 + m1] * wL[6208 + b * 4 + k2 * 2 + m2];
        sL[8448 + li] = s;
    }
    __syncthreads();

    // T1 tiled -> tuL[0:4096)
    {
        const int p0 = (tid >> 6) * 4, q0 = (tid & 63) * 4;
        float acc[4][4] = {};
#pragma unroll
        for (int a = 0; a < 16; ++a) {
            floatx4 pr = *reinterpret_cast<const floatx4*>(sL + a * 16 + p0);
            floatx4 qr = *reinterpret_cast<const floatx4*>(sL + 256 + a * 256 + q0);
#pragma unroll
            for (int r = 0; r < 4; ++r)
#pragma unroll
                for (int s = 0; s < 4; ++s) acc[r][s] += pr[r] * qr[s];
        }
#pragma unroll
        for (int r = 0; r < 4; ++r)
#pragma unroll
        for (int s = 0; s < 4; ++s) {
            int p = p0 + r, q = q0 + s;
            tuL[(q >> 4) * 256 + ((p >> 2) * 4 + ((q >> 2) & 3)) * 16 +
                (p & 3) * 4 + (q & 3)] = acc[r][s];
        }
    }
    // U tiled -> tuL[4096:8192)
    {
        const int r0 = (tid >> 2) * 4, q0 = (tid & 3) * 4;
        float acc[4][4] = {};
#pragma unroll
        for (int b = 0; b < 16; ++b) {
            floatx4 ar = *reinterpret_cast<const floatx4*>(sL + 4352 + (r0 >> 4) * 256 + b * 16 + (r0 & 15));
            floatx4 br = *reinterpret_cast<const floatx4*>(sL + 8448 + b * 16 + q0);
#pragma unroll
            for (int r = 0; r < 4; ++r)
#pragma unroll
                for (int s = 0; s < 4; ++s) acc[r][s] += ar[r] * br[s];
        }
#pragma unroll
        for (int r = 0; r < 4; ++r)
#pragma unroll
        for (int s = 0; s < 4; ++s)
            tuL[4096 + (r0 + r) * 16 + q0 + s] = acc[r][s];
    }
    __syncthreads();

    // W slice
    {
        int idx = blockIdx.x * 256 + tid;
        int J4 = idx & 255, I4 = idx >> 8;
        int I16 = I4 >> 4, kc = (I4 >> 2) & 3, k2v = I4 & 3;
        int mc = (J4 >> 2) & 3, m2v = J4 & 3;
        int J16 = J4 >> 4;
        const float* Uc = tuL + 4096 + (((kc * 4 + mc) * 4 + k2v) * 4 + m2v);
        float s = 0.f;
#pragma unroll
        for (int a = 0; a < 16; ++a)
            s += tuL[(a * 16 + I16) * 16 + J16] * Uc[a * 256];
        int nn = J4 >> 4, lr = J4 & 15, kq = I4 >> 5, gg = (I4 >> 3) & 3, jj = I4 & 7;
        Wf[(((nn * 8 + kq) * 64) + gg * 16 + lr) * 8 + jj] = (_Float16)(s * WSCALE);
    }
}

// ---- Main fused kernel: R13 pipeline (best, 62.6us) + SWAPPED MFMA OPERANDS.
// mfma(A=W-frag, B=x-frag): D transposes so lane holds y[x-row=lrow][W-col=
// g*4+r]. The dk-fold becomes in-register (4 FMA/strip, kv via 1 ds_read_b128)
// and the final reduce is over g only: 2 shfl_xor/set instead of 16, scalar
// stores. DS-pipe/set: 13.8K -> ~12.6K cyc < HBM 12.8K -> HBM-paced.
// Operand-swap safety: both A and B use the same lane->(idx,k) layout fn
// (validated by the current kernel; shared k-permutations cancel).
// Staging schedule byte-identical to R13: 8 sets x 16 rows/wave, single
// lo/hi buffer, issue s+2 after cvt, one barrier.
__global__ __launch_bounds__(512, 2)
void mpo_main(const float* __restrict__ x, const _Float16* __restrict__ Wf,
              const float* __restrict__ dk, const float* __restrict__ bias,
              float* __restrict__ out) {
    extern __shared__ _Float16 Wl[];                       // 65536 halves + 256 floats
    float* dkL = reinterpret_cast<float*>(Wl + 65536);

    const int tid  = threadIdx.x;
    const int lane = tid & 63;
    const int wave = tid >> 6;        // 0..7
    const int lrow = lane & 15;
    const int g    = lane >> 4;

    const long blockbase = (long)blockIdx.x * 1024;
    // wave's rows for set s: blockbase + s*128 + wave*16 + lrow
    const float* xb = x + (blockbase + wave * 16 + lrow) * 256 + g * 8;
    const int SET_STRIDE = 128 * 256;   // floats per set (128 rows)

    half8 a[8];
    floatx4 lo[8], hi[8];

#define SB()  __builtin_amdgcn_sched_barrier(0)
#define XLD(i, xn) do { const float* p_ = (xn) + (i) * 32;              \
                     lo[i] = *reinterpret_cast<const floatx4*>(p_);     \
                     hi[i] = *reinterpret_cast<const floatx4*>(p_ + 4); } while (0)
#define XLD_ALL(xn) do { XLD(0,xn); XLD(1,xn); XLD(2,xn); XLD(3,xn); \
                         XLD(4,xn); XLD(5,xn); XLD(6,xn); XLD(7,xn); } while (0)
#define XCVT(i) do { half8 f_;                                                \
                     f_[0] = (_Float16)lo[i][0]; f_[1] = (_Float16)lo[i][1];  \
                     f_[2] = (_Float16)lo[i][2]; f_[3] = (_Float16)lo[i][3];  \
                     f_[4] = (_Float16)hi[i][0]; f_[5] = (_Float16)hi[i][1];  \
                     f_[6] = (_Float16)hi[i][2]; f_[7] = (_Float16)hi[i][3];  \
                     a[i] = f_; } while (0)
#define XCVT_ALL() do { XCVT(0); XCVT(1); XCVT(2); XCVT(3); \
                        XCVT(4); XCVT(5); XCVT(6); XCVT(7); } while (0)

    // ---- prologue: issue set0; stage W+dk; barrier (drains set0 = fill) ----
    XLD_ALL(xb);
    SB();
    {
        const floatx4* src = reinterpret_cast<const floatx4*>(Wf);
        floatx4* dst = reinterpret_cast<floatx4*>(Wl);
#pragma unroll
        for (int i = 0; i < 16; ++i)
            dst[tid + i * 512] = src[tid + i * 512];
    }
    if (tid < 256) dkL[tid] = dk[tid];
    const float bs = bias[0];
    __syncthreads();   // the only barrier

    XCVT_ALL();                 // a <- set 0
    XLD_ALL(xb + SET_STRIDE);   // issue set 1
    SB();

    const half8* Wv = reinterpret_cast<const half8*>(Wl);
    const float* kvp = dkL + g * 4;

#pragma unroll 1
    for (int s = 0; s < 8; ++s) {
        float rp = 0.f;
#pragma unroll 1
        for (int n = 0; n < 16; ++n) {
            const floatx4 kv = *reinterpret_cast<const floatx4*>(kvp + n * 16);
            const half8* Wn = Wv + n * 512 + lane;
            floatx4 c = {0, 0, 0, 0};
#pragma unroll
            for (int kk = 0; kk < 8; ++kk)
                c = __builtin_amdgcn_mfma_f32_16x16x32_f16(Wn[kk * 64], a[kk], c, 0, 0, 0);
            rp += c[0] * c[0] * kv[0] + c[1] * c[1] * kv[1]
                + c[2] * c[2] * kv[2] + c[3] * c[3] * kv[3];
        }

        // rotate the pipeline: a <- set s+1, issue set s+2
        if (s < 7) { XCVT_ALL(); }
        if (s < 6) { XLD_ALL(xb + (s + 2) * SET_STRIDE); }
        SB();

        // reduce over g (W-col groups): 2 shfl; every lane then holds the
        // full sum for its x-row (lrow). g==0 lanes store.
        rp += __shfl_xor(rp, 16);
        rp += __shfl_xor(rp, 32);
        if (g == 0)
            out[blockbase + s * 128 + wave * 16 + lrow] = rp * WSCALE_INV + bs;
        SB();
    }
}

extern "C" void kernel_launch(void* const* d_in, const int* in_sizes, int n_in,
                              void* d_out, int out_size, void* d_ws, size_t ws_size,
                              hipStream_t stream) {
    const float* x    = (const float*)d_in[0];
    const float* w    = (const float*)d_in[1];
    const float* dk   = (const float*)d_in[2];
    const float* bias = (const float*)d_in[3];
    float* out = (float*)d_out;
    float* ws  = (float*)d_ws;

    _Float16* Wf16 = (_Float16*)(ws + WF16_OFF);

    // Allow 129 KB dynamic LDS for mpo_main (host-side attr; validated R5-R16).
    static bool attr_set = false;
    if (!attr_set) {
        hipFuncSetAttribute((const void*)mpo_main,
                            hipFuncAttributeMaxDynamicSharedMemorySize, 132096);
        attr_set = true;
    }

    // W contraction: ONE kernel (per-block redundant T1/U + W slice)
    mpo_prep<<<256, 256, 0, stream>>>(w, Wf16);

    // Main fused GEMM + square + dot: 256 blocks x 512 threads, 129 KB LDS
    mpo_main<<<256, 512, 132096, stream>>>(x, Wf16, dk, bias, out);
}

// Round 18
// 66.214 us; speedup vs baseline: 1.3911x; 1.0220x over previous
//
#include <hip/hip_runtime.h>
#include <hip/hip_bf16.h>

typedef _Float16 half8 __attribute__((ext_vector_type(8)));
typedef float    floatx4 __attribute__((ext_vector_type(4)));

#define WSCALE      4096.0f
#define WSCALE_INV  (1.0f/(4096.0f*4096.0f))

#define WF16_OFF 8192   // _Float16 offset into ws; 16B-aligned

// ---- Merged prep (validated R13-R17): 256 blocks x 256 threads; each block
// redundantly computes S0..S3 -> T1,U in LDS, then its 256-elem W slice.
__global__ __launch_bounds__(256)
void mpo_prep(const float* __restrict__ w, _Float16* __restrict__ Wf) {
    __shared__ __align__(16) float wL[6272];
    __shared__ __align__(16) float sL[8704];   // S0@0 S1@256 S2@4352 S3@8448
    __shared__ __align__(16) float tuL[8192];  // T1@0 U@4096
    const int tid = threadIdx.x;

    {
        const floatx4* s4 = reinterpret_cast<const floatx4*>(w);
        floatx4* d4 = reinterpret_cast<floatx4*>(wL);
        for (int i = tid; i < 1568; i += 256) d4[i] = s4[i];
    }
    __syncthreads();

    // S0 (cores 0x1 @0,64)
    {
        int li = tid;
        int mm = li & 3, kk = (li >> 2) & 3, c = li >> 4;
        int k1 = kk >> 1, k2 = kk & 1, m1 = mm >> 1, m2 = mm & 1;
        float s = 0.f;
#pragma unroll
        for (int b = 0; b < 16; ++b)
            s += wL[b * 4 + k1 * 2 + m1] * wL[64 + b * 64 + c * 4 + k2 * 2 + m2];
        sL[li] = s;
    }
    // S1 tiled (cores 2x3 @1088,2112)
    {
        const int i0 = (tid >> 4) * 4, j0 = (tid & 15) * 4;
        const float* Ab = wL + 1088 + (i0 >> 2) * 64;
        const float* Bb = wL + 2112 + j0;
        float acc[4][4] = {};
#pragma unroll
        for (int b = 0; b < 16; ++b) {
            floatx4 ar = *reinterpret_cast<const floatx4*>(Ab + b * 4);
            floatx4 br = *reinterpret_cast<const floatx4*>(Bb + b * 64);
#pragma unroll
            for (int r = 0; r < 4; ++r)
#pragma unroll
                for (int s = 0; s < 4; ++s) acc[r][s] += ar[r] * br[s];
        }
#pragma unroll
        for (int r = 0; r < 4; ++r)
#pragma unroll
        for (int s = 0; s < 4; ++s) {
            int i = i0 + r, j = j0 + s;
            sL[256 + (i >> 2) * 256 + (j >> 2) * 16 +
               ((i >> 1) & 1) * 8 + ((j >> 1) & 1) * 4 + (i & 1) * 2 + (j & 1)] = acc[r][s];
        }
    }
    // S2 tiled (cores 4x5 @3136,4160)
    {
        const int i0 = (tid >> 4) * 4, j0 = (tid & 15) * 4;
        const float* Ab = wL + 3136 + (i0 >> 2) * 64;
        const float* Bb = wL + 4160 + j0;
        float acc[4][4] = {};
#pragma unroll
        for (int b = 0; b < 16; ++b) {
            floatx4 ar = *reinterpret_cast<const floatx4*>(Ab + b * 4);
            floatx4 br = *reinterpret_cast<const floatx4*>(Bb + b * 64);
#pragma unroll
            for (int r = 0; r < 4; ++r)
#pragma unroll
                for (int s = 0; s < 4; ++s) acc[r][s] += ar[r] * br[s];
        }
#pragma unroll
        for (int r = 0; r < 4; ++r)
#pragma unroll
        for (int s = 0; s < 4; ++s) {
            int i = i0 + r, j = j0 + s;
            sL[4352 + (i >> 2) * 256 + (j >> 2) * 16 +
               ((i >> 1) & 1) * 8 + ((j >> 1) & 1) * 4 + (i & 1) * 2 + (j & 1)] = acc[r][s];
        }
    }
    // S3 (cores 6x7 @5184,6208)
    {
        int li = tid;
        int mm = li & 3, kk = (li >> 2) & 3, a = li >> 4;
        int k1 = kk >> 1, k2 = kk & 1, m1 = mm >> 1, m2 = mm & 1;
        float s = 0.f;
#pragma unroll
        for (int b = 0; b < 16; ++b)
            s += wL[5184 + a * 64 + b * 4 + k1 * 2 + m1] * wL[6208 + b * 4 + k2 * 2 + m2];
        sL[8448 + li] = s;
    }
    __syncthreads();

    // T1 tiled -> tuL[0:4096)
    {
        const int p0 = (tid >> 6) * 4, q0 = (tid & 63) * 4;
        float acc[4][4] = {};
#pragma unroll
        for (int a = 0; a < 16; ++a) {
            floatx4 pr = *reinterpret_cast<const floatx4*>(sL + a * 16 + p0);
            floatx4 qr = *reinterpret_cast<const floatx4*>(sL + 256 + a * 256 + q0);
#pragma unroll
            for (int r = 0; r < 4; ++r)
#pragma unroll
                for (int s = 0; s < 4; ++s) acc[r][s] += pr[r] * qr[s];
        }
#pragma unroll
        for (int r = 0; r < 4; ++r)
#pragma unroll
        for (int s = 0; s < 4; ++s) {
            int p = p0 + r, q = q0 + s;
            tuL[(q >> 4) * 256 + ((p >> 2) * 4 + ((q >> 2) & 3)) * 16 +
                (p & 3) * 4 + (q & 3)] = acc[r][s];
        }
    }
    // U tiled -> tuL[4096:8192)
    {
        const int r0 = (tid >> 2) * 4, q0 = (tid & 3) * 4;
        float acc[4][4] = {};
#pragma unroll
        for (int b = 0; b < 16; ++b) {
            floatx4 ar = *reinterpret_cast<const floatx4*>(sL + 4352 + (r0 >> 4) * 256 + b * 16 + (r0 & 15));
            floatx4 br = *reinterpret_cast<const floatx4*>(sL + 8448 + b * 16 + q0);
#pragma unroll
            for (int r = 0; r < 4; ++r)
#pragma unroll
                for (int s = 0; s < 4; ++s) acc[r][s] += ar[r] * br[s];
        }
#pragma unroll
        for (int r = 0; r < 4; ++r)
#pragma unroll
        for (int s = 0; s < 4; ++s)
            tuL[4096 + (r0 + r) * 16 + q0 + s] = acc[r][s];
    }
    __syncthreads();

    // W slice
    {
        int idx = blockIdx.x * 256 + tid;
        int J4 = idx & 255, I4 = idx >> 8;
        int I16 = I4 >> 4, kc = (I4 >> 2) & 3, k2v = I4 & 3;
        int mc = (J4 >> 2) & 3, m2v = J4 & 3;
        int J16 = J4 >> 4;
        const float* Uc = tuL + 4096 + (((kc * 4 + mc) * 4 + k2v) * 4 + m2v);
        float s = 0.f;
#pragma unroll
        for (int a = 0; a < 16; ++a)
            s += tuL[(a * 16 + I16) * 16 + J16] * Uc[a * 256];
        int nn = J4 >> 4, lr = J4 & 15, kq = I4 >> 5, gg = (I4 >> 3) & 3, jj = I4 & 7;
        Wf[(((nn * 8 + kq) * 64) + gg * 16 + lr) * 8 + jj] = (_Float16)(s * WSCALE);
    }
}

// ---- Main fused kernel: R13 (62.6us best) + 2-DEEP prefetch, DE-CONFOUNDED.
// Identical to R13 in every respect (kreg hoisted! same n-loop, same reduce,
// one barrier) except: second fixed-parity lo/hi buffer so sets s+1 AND s+2
// are in flight during nloop(s); the cvt consumes a set aged ~2 n-loops ->
// HBM queue jitter absorbed, wait is counted not a drain. ~200 VGPR.
// (R16 tested this WITH a dk-from-LDS confound that cost ~5us; R16/R17 both
// +5.1 vs R13 with that confound as the common factor.)
__global__ __launch_bounds__(512, 2)
void mpo_main(const float* __restrict__ x, const _Float16* __restrict__ Wf,
              const float* __restrict__ dk, const float* __restrict__ bias,
              float* __restrict__ out) {
    extern __shared__ _Float16 Wl[];                       // 65536 halves + 256 floats
    float* dkL = reinterpret_cast<float*>(Wl + 65536);

    const int tid  = threadIdx.x;
    const int lane = tid & 63;
    const int wave = tid >> 6;        // 0..7
    const int lrow = lane & 15;
    const int g    = lane >> 4;

    const long blockbase = (long)blockIdx.x * 1024;
    // wave's rows for set s: blockbase + s*128 + wave*16 + lrow
    const float* xs = x + (blockbase + wave * 16 + lrow) * 256 + g * 8;
    const int SS = 128 * 256;         // floats per set (128 rows)

    half8 a[8];
    floatx4 loA[8], hiA[8], loB[8], hiB[8];

#define SB()  __builtin_amdgcn_sched_barrier(0)
#define XLD8(lo, hi, xn) do { _Pragma("unroll")                          \
    for (int i_ = 0; i_ < 8; ++i_) {                                     \
        const float* p_ = (xn) + i_ * 32;                                \
        lo[i_] = *reinterpret_cast<const floatx4*>(p_);                  \
        hi[i_] = *reinterpret_cast<const floatx4*>(p_ + 4);              \
    } } while (0)
#define XCVT8(dst, lo, hi) do { _Pragma("unroll")                        \
    for (int i_ = 0; i_ < 8; ++i_) {                                     \
        half8 f_;                                                        \
        f_[0] = (_Float16)lo[i_][0]; f_[1] = (_Float16)lo[i_][1];        \
        f_[2] = (_Float16)lo[i_][2]; f_[3] = (_Float16)lo[i_][3];        \
        f_[4] = (_Float16)hi[i_][0]; f_[5] = (_Float16)hi[i_][1];        \
        f_[6] = (_Float16)hi[i_][2]; f_[7] = (_Float16)hi[i_][3];        \
        dst[i_] = f_;                                                    \
    } } while (0)

#define NLOOP(rp) do {                                                           \
    _Pragma("unroll 1")                                                          \
    for (int n = 0; n < 16; ++n) {                                               \
        const half8* Wn = Wv + n * 512 + lane;                                   \
        floatx4 c0 = {0, 0, 0, 0};                                               \
        _Pragma("unroll")                                                        \
        for (int kk = 0; kk < 8; ++kk)                                           \
            c0 = __builtin_amdgcn_mfma_f32_16x16x32_f16(a[kk], Wn[kk * 64], c0, 0, 0, 0); \
        const float kv = kreg[n];                                                \
        _Pragma("unroll")                                                        \
        for (int r = 0; r < 4; ++r) rp[r] += c0[r] * c0[r] * kv;                 \
    } } while (0)

#define REDUCE_STORE(rp, s) do {                                                 \
    _Pragma("unroll")                                                            \
    for (int r = 0; r < 4; ++r) {                                                \
        float v = rp[r];                                                         \
        v += __shfl_xor(v, 1); v += __shfl_xor(v, 2);                            \
        v += __shfl_xor(v, 4); v += __shfl_xor(v, 8);                            \
        rp[r] = v;                                                               \
    }                                                                            \
    if (lrow == 0) {                                                             \
        floatx4 o;                                                               \
        _Pragma("unroll")                                                        \
        for (int r = 0; r < 4; ++r) o[r] = rp[r] * WSCALE_INV + bs;              \
        *reinterpret_cast<floatx4*>(out + blockbase + (s) * 128 + wave * 16 + g * 4) = o; \
    } } while (0)

    // ---- prologue: issue set0(A), set1(B); stage W + dk; barrier ----
    XLD8(loA, hiA, xs);
    XLD8(loB, hiB, xs + SS);
    SB();
    {
        const floatx4* src = reinterpret_cast<const floatx4*>(Wf);
        floatx4* dst = reinterpret_cast<floatx4*>(Wl);
#pragma unroll
        for (int i = 0; i < 16; ++i)
            dst[tid + i * 512] = src[tid + i * 512];
    }
    if (tid < 256) dkL[tid] = dk[tid];
    const float bs = bias[0];
    __syncthreads();   // the only barrier

    float kreg[16];
#pragma unroll
    for (int n = 0; n < 16; ++n) kreg[n] = dkL[n * 16 + lrow];

    XCVT8(a, loA, hiA);            // a <- set 0
    XLD8(loA, hiA, xs + 2 * SS);   // issue set 2 -> in flight: set1, set2
    SB();

    const half8* Wv = reinterpret_cast<const half8*>(Wl);

#pragma unroll 1
    for (int j = 0; j < 4; ++j) {
        // ---- even set s = 2j (a holds it; bufB has s+1, bufA has s+2) ----
        {
            float rp[4] = {0, 0, 0, 0};
            NLOOP(rp);
            XCVT8(a, loB, hiB);                              // a <- set 2j+1 (aged 2 nloops)
            if (2 * j + 3 < 8) { XLD8(loB, hiB, xs + (2 * j + 3) * SS); }
            SB();
            REDUCE_STORE(rp, 2 * j);
            SB();
        }
        // ---- odd set s = 2j+1 (bufA has s+2) ----
        {
            float rp[4] = {0, 0, 0, 0};
            NLOOP(rp);
            if (2 * j + 2 < 8) { XCVT8(a, loA, hiA); }       // a <- set 2j+2
            if (2 * j + 4 < 8) { XLD8(loA, hiA, xs + (2 * j + 4) * SS); }
            SB();
            REDUCE_STORE(rp, 2 * j + 1);
            SB();
        }
    }
}

extern "C" void kernel_launch(void* const* d_in, const int* in_sizes, int n_in,
                              void* d_out, int out_size, void* d_ws, size_t ws_size,
                              hipStream_t stream) {
    const float* x    = (const float*)d_in[0];
    const float* w    = (const float*)d_in[1];
    const float* dk   = (const float*)d_in[2];
    const float* bias = (const float*)d_in[3];
    float* out = (float*)d_out;
    float* ws  = (float*)d_ws;

    _Float16* Wf16 = (_Float16*)(ws + WF16_OFF);

    // Allow 129 KB dynamic LDS for mpo_main (host-side attr; validated R5-R17).
    static bool attr_set = false;
    if (!attr_set) {
        hipFuncSetAttribute((const void*)mpo_main,
                            hipFuncAttributeMaxDynamicSharedMemorySize, 132096);
        attr_set = true;
    }

    // W contraction: ONE kernel (per-block redundant T1/U + W slice)
    mpo_prep<<<256, 256, 0, stream>>>(w, Wf16);

    // Main fused GEMM + square + dot: 256 blocks x 512 threads, 129 KB LDS
    mpo_main<<<256, 512, 132096, stream>>>(x, Wf16, dk, bias, out);
}